// Round 7
// baseline (17579.451 us; speedup 1.0000x reference)
//
#include <hip/hip_runtime.h>
#include <hip/hip_bf16.h>
#include <math.h>

#define T_STEPS 256
#define NB 4096

__global__ __launch_bounds__(256, 2)
void rssm_kernel(const float* __restrict__ X, const float* __restrict__ A,
                 const float* __restrict__ H0, const float* __restrict__ G,
                 const float* __restrict__ Wih, const float* __restrict__ bih,
                 const float* __restrict__ Whh, const float* __restrict__ bhh,
                 const float* __restrict__ Wenc, const float* __restrict__ benc,
                 const float* __restrict__ Wdec, const float* __restrict__ bdec,
                 float* __restrict__ out)   // d_out is FP32
{
    // fp32 weight tables in LDS (exact values; converted to fp64 at use)
    __shared__ float  sWihz[96][65];   // W_ih z-part, gathered by one-hot column (bank = i + col)
    __shared__ float  sWenchT[32][64]; // enc h-part transposed [k][logit]
    __shared__ float  sWenceT[10][64]; // enc e-part transposed
    __shared__ float  sWdech[10][37];  // dec h-part rows (pad 37: banks 5r+k distinct for r<10)
    __shared__ float  sWdecz[10][65];  // dec z-part, gathered
    __shared__ double sHd[8][33];      // per-element fp64 h state (broadcast reads; intra-wave only)

    const int tid = threadIdx.x;
    const int i   = tid & 31;          // component lane within element
    const int e   = tid >> 5;          // element slot in block (0..7)
    const int n   = blockIdx.x * 8 + e;

    for (int idx = tid; idx < 96*64; idx += 256){ int r = idx >> 6, c = idx & 63; sWihz[r][c] = Wih[r*80 + c]; }
    for (int idx = tid; idx < 32*64; idx += 256){ int k = idx >> 6, j = idx & 63; sWenchT[k][j] = Wenc[j*42 + k]; }
    for (int idx = tid; idx < 10*64; idx += 256){ int k = idx >> 6, j = idx & 63; sWenceT[k][j] = Wenc[j*42 + 32 + k]; }
    for (int idx = tid; idx < 10*32; idx += 256){ int o = idx >> 5, k = idx & 31; sWdech[o][k] = Wdec[o*96 + k]; }
    for (int idx = tid; idx < 10*64; idx += 256){ int o = idx >> 6, c = idx & 63; sWdecz[o][c] = Wdec[o*96 + 32 + c]; }
    __syncthreads();

    // W_hh rows {i, 32+i, 64+i} and W_ih a-part rows in fp32 registers (exact input values)
    float whh[3][32];
    float wiha[3][16];
    #pragma unroll
    for (int s = 0; s < 3; ++s){
        const float4* row = reinterpret_cast<const float4*>(Whh + (s*32 + i)*32);
        #pragma unroll
        for (int c = 0; c < 8; ++c){
            float4 v = row[c];
            whh[s][4*c+0]=v.x; whh[s][4*c+1]=v.y; whh[s][4*c+2]=v.z; whh[s][4*c+3]=v.w;
        }
        const float4* arw = reinterpret_cast<const float4*>(Wih + (s*32 + i)*80 + 64);
        #pragma unroll
        for (int c = 0; c < 4; ++c){
            float4 v = arw[c];
            wiha[s][4*c+0]=v.x; wiha[s][4*c+1]=v.y; wiha[s][4*c+2]=v.z; wiha[s][4*c+3]=v.w;
        }
    }

    // biases (r,z gates merge b_ih+b_hh; n gate split: b_hh[n] sits inside r*h_n)
    const double br  = (double)bih[i]      + (double)bhh[i];
    const double bz  = (double)bih[32+i]   + (double)bhh[32+i];
    const double bni = (double)bih[64+i];
    const double bnh = (double)bhh[64+i];
    const double be0 = (double)benc[2*i], be1 = (double)benc[2*i+1];
    const float  bd  = (i < 10) ? bdec[i] : 0.0f;
    const int    drow = (i < 10) ? i : 9;  // dec weight row (lanes >=10 discard)

    // h state lives in LDS; each lane owns component i
    double hown = (double)H0[(size_t)n * 32 + i];
    sHd[e][i] = hown;                  // intra-wave visibility; no barrier needed

    int zsel[8];                       // winning flat column (0..63) per z-group

    const size_t HOFF = (size_t)T_STEPS * NB * 10;   // x_logits elements
    const size_t ZOFF = HOFF + (size_t)T_STEPS * NB * 32;
    const int base = tid & 32;         // element's lane base within the wave

    #pragma unroll 1
    for (int t = 0; t < T_STEPS; ++t){
        const size_t tn = (size_t)t * NB + n;

        // loads for this step (independent of GRU)
        float2 g2 = *reinterpret_cast<const float2*>(G + tn*64 + 2*i);
        float ex[10];
        {
            const float* xr = X + tn*10;
            #pragma unroll
            for (int c = 0; c < 5; ++c){
                float2 v = *reinterpret_cast<const float2*>(xr + 2*c);
                ex[2*c] = v.x; ex[2*c+1] = v.y;
            }
        }

        if (t > 0){
            // ---- GRU (fp64): h_t = gru([z_{t-1}, a_{t-1}], h_{t-1}) ----
            float ar[16];
            {
                const float4* arow = reinterpret_cast<const float4*>(A + ((size_t)(t-1)*NB + n)*16);
                #pragma unroll
                for (int c = 0; c < 4; ++c){
                    float4 v = arow[c];
                    ar[4*c+0]=v.x; ar[4*c+1]=v.y; ar[4*c+2]=v.z; ar[4*c+3]=v.w;
                }
            }
            double gr = br, gz = bz, gn = bni, hn = bnh;
            #pragma unroll
            for (int g = 0; g < 8; ++g){   // one-hot z part: gather selected columns
                int col = zsel[g];
                gr += (double)sWihz[i][col];
                gz += (double)sWihz[32+i][col];
                gn += (double)sWihz[64+i][col];
            }
            #pragma unroll
            for (int k = 0; k < 16; ++k){  // dense a part (register weights)
                double ak = (double)ar[k];
                gr = fma((double)wiha[0][k], ak, gr);
                gz = fma((double)wiha[1][k], ak, gz);
                gn = fma((double)wiha[2][k], ak, gn);
            }
            #pragma unroll
            for (int k = 0; k < 32; ++k){  // hidden part: h broadcast from LDS, weights in regs
                double hk = sHd[e][k];
                gr = fma((double)whh[0][k], hk, gr);
                gz = fma((double)whh[1][k], hk, gz);
                hn = fma((double)whh[2][k], hk, hn);
            }
            double r   = 1.0 / (1.0 + exp(-gr));
            double zg  = 1.0 / (1.0 + exp(-gz));
            double arg = gn + r * hn;
            double e2  = exp(2.0 * arg);
            double nn  = 1.0 - 2.0 / (e2 + 1.0);
            hown = (1.0 - zg) * nn + zg * hown;

            // publish h_new (all reads of h_old are in program order above; same wave)
            sHd[e][i] = hown;
        }

        // h_all output (fp32)
        out[HOFF + tn*32 + i] = (float)hown;

        // ---- ENC (fp64 logits) + DEC h-part, sharing the h broadcast reads ----
        double l0 = be0, l1 = be1;
        double dacc = (double)bd;
        #pragma unroll
        for (int k = 0; k < 32; ++k){
            double hk = sHd[e][k];
            float2 w = *reinterpret_cast<const float2*>(&sWenchT[k][2*i]);
            l0 = fma((double)w.x, hk, l0);
            l1 = fma((double)w.y, hk, l1);
            dacc = fma((double)sWdech[drow][k], hk, dacc);
        }
        #pragma unroll
        for (int k = 0; k < 10; ++k){
            float2 w = *reinterpret_cast<const float2*>(&sWenceT[k][2*i]);
            double ek = (double)ex[k];
            l0 = fma((double)w.x, ek, l0);
            l1 = fma((double)w.y, ek, l1);
        }
        double y0 = l0 + (double)g2.x, y1 = l1 + (double)g2.y;
        double m; int idxv;
        if (y1 > y0){ m = y1; idxv = 2*i + 1; } else { m = y0; idxv = 2*i; }
        #pragma unroll
        for (int d = 1; d <= 2; d <<= 1){   // butterfly argmax over the 4-lane cluster
            double mo = __shfl_xor(m, d, 64);
            int    io = __shfl_xor(idxv, d, 64);
            if (mo > m || (mo == m && io < idxv)){ m = mo; idxv = io; }
        }

        // z one-hot output (fp32)
        {
            float2 zv;
            zv.x = (idxv == 2*i    ) ? 1.0f : 0.0f;
            zv.y = (idxv == 2*i + 1) ? 1.0f : 0.0f;
            *reinterpret_cast<float2*>(out + ZOFF + tn*64 + 2*i) = zv;
        }

        // distribute the 8 group winners to every lane of the element
        #pragma unroll
        for (int g = 0; g < 8; ++g){
            zsel[g] = __shfl(idxv, base + 4*g, 64);
        }

        // ---- DEC z-part + store (lanes 0..9) ----
        if (i < 10){
            double acc = dacc;
            #pragma unroll
            for (int g = 0; g < 8; ++g) acc += (double)sWdecz[i][zsel[g]];
            out[tn*10 + i] = (float)acc;
        }
    }
}

extern "C" void kernel_launch(void* const* d_in, const int* in_sizes, int n_in,
                              void* d_out, int out_size, void* d_ws, size_t ws_size,
                              hipStream_t stream)
{
    // Defensive input binding by unique element count (no-op if dict order holds).
    const float *x   = (const float*)d_in[0];
    const float *a   = (const float*)d_in[1];
    const float *h0  = (const float*)d_in[2];
    const float *g   = (const float*)d_in[3];
    const float *wih = (const float*)d_in[4];
    const float *bih = (const float*)d_in[5];
    const float *whh = (const float*)d_in[6];
    const float *bhh = (const float*)d_in[7];
    const float *wenc= (const float*)d_in[8];
    const float *benc= (const float*)d_in[9];
    const float *wdec= (const float*)d_in[10];
    const float *bdec= (const float*)d_in[11];

    if (n_in == 12) {
        const float *b96a = nullptr, *b96b = nullptr;
        const float *tx=nullptr,*ta=nullptr,*th0=nullptr,*tg=nullptr,*twih=nullptr,
                    *twhh=nullptr,*twenc=nullptr,*tbenc=nullptr,*twdec=nullptr,*tbdec=nullptr;
        for (int k = 0; k < 12; ++k) {
            const float* p = (const float*)d_in[k];
            switch (in_sizes[k]) {
                case 10485760: tx = p;    break;  // x
                case 16777216: ta = p;    break;  // a
                case 131072:   th0 = p;   break;  // h0
                case 67108864: tg = p;    break;  // gumbel
                case 7680:     twih = p;  break;  // W_ih
                case 3072:     twhh = p;  break;  // W_hh
                case 2688:     twenc = p; break;  // W_enc
                case 64:       tbenc = p; break;  // b_enc
                case 960:      twdec = p; break;  // W_dec
                case 10:       tbdec = p; break;  // b_dec
                case 96:       if (!b96a) b96a = p; else b96b = p; break; // b_ih / b_hh (both zero)
                default: break;
            }
        }
        if (tx && ta && th0 && tg && twih && twhh && twenc && tbenc && twdec && tbdec && b96a && b96b) {
            x = tx; a = ta; h0 = th0; g = tg;
            wih = twih; whh = twhh; wenc = twenc; benc = tbenc; wdec = twdec; bdec = tbdec;
            bih = b96a; bhh = b96b;
        }
    }

    rssm_kernel<<<512, 256, 0, stream>>>(
        x, a, h0, g, wih, bih, whh, bhh, wenc, benc, wdec, bdec,
        (float*)d_out);
}

// Round 9
// 1157.617 us; speedup vs baseline: 15.1859x; 15.1859x over previous
//
#include <hip/hip_runtime.h>
#include <math.h>

#define T_STEPS 256
#define NB 4096

__global__ __launch_bounds__(256, 2)
void rssm_kernel(const float* __restrict__ X, const float* __restrict__ A,
                 const float* __restrict__ H0, const float* __restrict__ G,
                 const float* __restrict__ Wih, const float* __restrict__ bih,
                 const float* __restrict__ Whh, const float* __restrict__ bhh,
                 const float* __restrict__ Wenc, const float* __restrict__ benc,
                 const float* __restrict__ Wdec, const float* __restrict__ bdec,
                 float* __restrict__ out)   // d_out is FP32
{
    // ALL weights in LDS -> per-lane register demand ~110 VGPRs, no spill.
    // LDS total: 24960+6528+12672+8192+2560+1480+2600+2112 = 61104 B < 64 KB.
    __shared__ float  sWihz[96][65];   // W_ih z-part, gathered by column (65 pad: bank r+c)
    __shared__ float  sWiha[96][17];   // W_ih a-part, 16 cols + pad
    __shared__ float  sWhh [96][33];   // W_hh, 32 cols + pad (bank i+k distinct across lanes)
    __shared__ float  sWenchT[32][64]; // enc h-part transposed [k][logit]
    __shared__ float  sWenceT[10][64]; // enc e-part transposed
    __shared__ float  sWdech[10][37];  // dec h-part rows
    __shared__ float  sWdecz[10][65];  // dec z-part, gathered
    __shared__ double sHd[8][33];      // per-element fp64 h state (broadcast reads; intra-wave)

    const int tid = threadIdx.x;
    const int i   = tid & 31;          // component lane within element
    const int e   = tid >> 5;          // element slot in block (0..7)
    const int n   = blockIdx.x * 8 + e;

    for (int idx = tid; idx < 96*64; idx += 256){ int r = idx >> 6, c = idx & 63; sWihz[r][c] = Wih[r*80 + c]; }
    for (int idx = tid; idx < 96*16; idx += 256){ int r = idx >> 4, k = idx & 15; sWiha[r][k] = Wih[r*80 + 64 + k]; }
    for (int idx = tid; idx < 96*32; idx += 256){ int r = idx >> 5, k = idx & 31; sWhh[r][k] = Whh[r*32 + k]; }
    for (int idx = tid; idx < 32*64; idx += 256){ int k = idx >> 6, j = idx & 63; sWenchT[k][j] = Wenc[j*42 + k]; }
    for (int idx = tid; idx < 10*64; idx += 256){ int k = idx >> 6, j = idx & 63; sWenceT[k][j] = Wenc[j*42 + 32 + k]; }
    for (int idx = tid; idx < 10*32; idx += 256){ int o = idx >> 5, k = idx & 31; sWdech[o][k] = Wdec[o*96 + k]; }
    for (int idx = tid; idx < 10*64; idx += 256){ int o = idx >> 6, c = idx & 63; sWdecz[o][c] = Wdec[o*96 + 32 + c]; }
    __syncthreads();

    // biases (r,z gates merge b_ih+b_hh; n gate split: b_hh[n] sits inside r*h_n)
    const double br  = (double)bih[i]      + (double)bhh[i];
    const double bz  = (double)bih[32+i]   + (double)bhh[32+i];
    const double bni = (double)bih[64+i];
    const double bnh = (double)bhh[64+i];
    const double be0 = (double)benc[2*i], be1 = (double)benc[2*i+1];
    const float  bd  = (i < 10) ? bdec[i] : 0.0f;
    const int    drow = (i < 10) ? i : 9;  // dec weight row (lanes >=10 discard)

    // h state lives in LDS; each lane owns component i
    double hown = (double)H0[(size_t)n * 32 + i];
    sHd[e][i] = hown;                  // intra-wave visibility; no barrier needed

    int zsel[8];                       // winning flat column (0..63) per z-group

    const size_t HOFF = (size_t)T_STEPS * NB * 10;   // x_logits elements
    const size_t ZOFF = HOFF + (size_t)T_STEPS * NB * 32;
    const int base = tid & 32;         // element's lane base within the wave

    // ---- software-prefetched step inputs (hide HBM latency under compute) ----
    float2 g2;  float ex[10];  float ar[16] = {};
    g2 = *reinterpret_cast<const float2*>(G + (size_t)n*64 + 2*i);   // G[t=0]
    {
        const float* xr = X + (size_t)n*10;                          // X[t=0]
        #pragma unroll
        for (int c = 0; c < 5; ++c){
            float2 v = *reinterpret_cast<const float2*>(xr + 2*c);
            ex[2*c] = v.x; ex[2*c+1] = v.y;
        }
    }

    #pragma unroll 1
    for (int t = 0; t < T_STEPS; ++t){
        const size_t tn = (size_t)t * NB + n;

        // ---- prefetch NEXT step's inputs first (used ~2000 cycles later) ----
        const int tp = (t + 1 < T_STEPS) ? t + 1 : t;   // clamp (wave-uniform)
        const size_t tpn = (size_t)tp * NB + n;
        float2 g2n = *reinterpret_cast<const float2*>(G + tpn*64 + 2*i);
        float exn[10];
        {
            const float* xr = X + tpn*10;
            #pragma unroll
            for (int c = 0; c < 5; ++c){
                float2 v = *reinterpret_cast<const float2*>(xr + 2*c);
                exn[2*c] = v.x; exn[2*c+1] = v.y;
            }
        }
        float arn[16];   // A[t], consumed by next iteration's GRU
        {
            const float4* arow = reinterpret_cast<const float4*>(A + tn*16);
            #pragma unroll
            for (int c = 0; c < 4; ++c){
                float4 v = arow[c];
                arn[4*c+0]=v.x; arn[4*c+1]=v.y; arn[4*c+2]=v.z; arn[4*c+3]=v.w;
            }
        }

        if (t > 0){
            // ---- GRU (fp64): h_t = gru([z_{t-1}, a_{t-1}], h_{t-1}) ----
            double gr = br, gz = bz, gn = bni, hn = bnh;
            #pragma unroll
            for (int g = 0; g < 8; ++g){   // one-hot z part: gather selected columns
                int col = zsel[g];
                gr += (double)sWihz[i][col];
                gz += (double)sWihz[32+i][col];
                gn += (double)sWihz[64+i][col];
            }
            #pragma unroll
            for (int k = 0; k < 16; ++k){  // dense a part (ar = A[t-1], prefetched)
                double ak = (double)ar[k];
                gr = fma((double)sWiha[i][k],    ak, gr);
                gz = fma((double)sWiha[32+i][k], ak, gz);
                gn = fma((double)sWiha[64+i][k], ak, gn);
            }
            #pragma unroll
            for (int k = 0; k < 32; ++k){  // hidden part: h broadcast from LDS
                double hk = sHd[e][k];
                gr = fma((double)sWhh[i][k],    hk, gr);
                gz = fma((double)sWhh[32+i][k], hk, gz);
                hn = fma((double)sWhh[64+i][k], hk, hn);
            }
            double r   = 1.0 / (1.0 + exp(-gr));
            double zg  = 1.0 / (1.0 + exp(-gz));
            double arg = gn + r * hn;
            double e2  = exp(2.0 * arg);
            double nn  = 1.0 - 2.0 / (e2 + 1.0);
            hown = (1.0 - zg) * nn + zg * hown;

            // publish h_new (all reads of h_old are in program order above; same wave)
            sHd[e][i] = hown;
        }

        // h_all output (fp32)
        out[HOFF + tn*32 + i] = (float)hown;

        // ---- ENC (fp64 logits) + DEC h-part, sharing the h broadcast reads ----
        double l0 = be0, l1 = be1;
        double dacc = (double)bd;
        #pragma unroll
        for (int k = 0; k < 32; ++k){
            double hk = sHd[e][k];
            float2 w = *reinterpret_cast<const float2*>(&sWenchT[k][2*i]);
            l0 = fma((double)w.x, hk, l0);
            l1 = fma((double)w.y, hk, l1);
            dacc = fma((double)sWdech[drow][k], hk, dacc);
        }
        #pragma unroll
        for (int k = 0; k < 10; ++k){
            float2 w = *reinterpret_cast<const float2*>(&sWenceT[k][2*i]);
            double ek = (double)ex[k];
            l0 = fma((double)w.x, ek, l0);
            l1 = fma((double)w.y, ek, l1);
        }
        double y0 = l0 + (double)g2.x, y1 = l1 + (double)g2.y;
        double m; int idxv;
        if (y1 > y0){ m = y1; idxv = 2*i + 1; } else { m = y0; idxv = 2*i; }
        #pragma unroll
        for (int d = 1; d <= 2; d <<= 1){   // butterfly argmax over the 4-lane cluster
            double mo = __shfl_xor(m, d, 64);
            int    io = __shfl_xor(idxv, d, 64);
            if (mo > m || (mo == m && io < idxv)){ m = mo; idxv = io; }
        }

        // z one-hot output (fp32)
        {
            float2 zv;
            zv.x = (idxv == 2*i    ) ? 1.0f : 0.0f;
            zv.y = (idxv == 2*i + 1) ? 1.0f : 0.0f;
            *reinterpret_cast<float2*>(out + ZOFF + tn*64 + 2*i) = zv;
        }

        // distribute the 8 group winners to every lane of the element
        #pragma unroll
        for (int g = 0; g < 8; ++g){
            zsel[g] = __shfl(idxv, base + 4*g, 64);
        }

        // ---- DEC z-part + store (lanes 0..9) ----
        if (i < 10){
            double acc = dacc;
            #pragma unroll
            for (int g = 0; g < 8; ++g) acc += (double)sWdecz[i][zsel[g]];
            out[tn*10 + i] = (float)acc;
        }

        // rotate prefetched inputs into place for the next iteration
        g2 = g2n;
        #pragma unroll
        for (int k = 0; k < 10; ++k) ex[k] = exn[k];
        #pragma unroll
        for (int k = 0; k < 16; ++k) ar[k] = arn[k];
    }
}

extern "C" void kernel_launch(void* const* d_in, const int* in_sizes, int n_in,
                              void* d_out, int out_size, void* d_ws, size_t ws_size,
                              hipStream_t stream)
{
    // Defensive input binding by unique element count (no-op if dict order holds).
    const float *x   = (const float*)d_in[0];
    const float *a   = (const float*)d_in[1];
    const float *h0  = (const float*)d_in[2];
    const float *g   = (const float*)d_in[3];
    const float *wih = (const float*)d_in[4];
    const float *bih = (const float*)d_in[5];
    const float *whh = (const float*)d_in[6];
    const float *bhh = (const float*)d_in[7];
    const float *wenc= (const float*)d_in[8];
    const float *benc= (const float*)d_in[9];
    const float *wdec= (const float*)d_in[10];
    const float *bdec= (const float*)d_in[11];

    if (n_in == 12) {
        const float *b96a = nullptr, *b96b = nullptr;
        const float *tx=nullptr,*ta=nullptr,*th0=nullptr,*tg=nullptr,*twih=nullptr,
                    *twhh=nullptr,*twenc=nullptr,*tbenc=nullptr,*twdec=nullptr,*tbdec=nullptr;
        for (int k = 0; k < 12; ++k) {
            const float* p = (const float*)d_in[k];
            switch (in_sizes[k]) {
                case 10485760: tx = p;    break;  // x
                case 16777216: ta = p;    break;  // a
                case 131072:   th0 = p;   break;  // h0
                case 67108864: tg = p;    break;  // gumbel
                case 7680:     twih = p;  break;  // W_ih
                case 3072:     twhh = p;  break;  // W_hh
                case 2688:     twenc = p; break;  // W_enc
                case 64:       tbenc = p; break;  // b_enc
                case 960:      twdec = p; break;  // W_dec
                case 10:       tbdec = p; break;  // b_dec
                case 96:       if (!b96a) b96a = p; else b96b = p; break; // b_ih / b_hh (both zero)
                default: break;
            }
        }
        if (tx && ta && th0 && tg && twih && twhh && twenc && tbenc && twdec && tbdec && b96a && b96b) {
            x = tx; a = ta; h0 = th0; g = tg;
            wih = twih; whh = twhh; wenc = twenc; benc = tbenc; wdec = twdec; bdec = tbdec;
            bih = b96a; bhh = b96b;
        }
    }

    rssm_kernel<<<512, 256, 0, stream>>>(
        x, a, h0, g, wih, bih, whh, bhh, wenc, benc, wdec, bdec,
        (float*)d_out);
}